// Round 1
// 853.360 us; speedup vs baseline: 1.0543x; 1.0543x over previous
//
#include <hip/hip_runtime.h>
#include <hip/hip_bf16.h>

typedef unsigned short u16;
typedef __attribute__((ext_vector_type(8))) short short8;   // 8 bf16 (4 VGPRs) — MFMA A/B frag
typedef __attribute__((ext_vector_type(4))) float floatx4;  // MFMA C/D frag

#define LN_EPS 1e-5f

__device__ __forceinline__ float bf2f(u16 u) {
    unsigned int i = ((unsigned int)u) << 16;
    float f; __builtin_memcpy(&f, &i, 4); return f;
}
__device__ __forceinline__ u16 f2bf(float f) {
    __hip_bfloat16 h = __float2bfloat16(f);   // RNE
    u16 u; __builtin_memcpy(&u, &h, 2); return u;
}

// async global->LDS, 16 B per lane; lds dest must be wave-uniform (HW adds lane*16)
__device__ __forceinline__ void gl_lds16(const u16* g, u16* l) {
    __builtin_amdgcn_global_load_lds(
        (const __attribute__((address_space(1))) void*)(const void*)g,
        (__attribute__((address_space(3))) void*)(void*)l,
        16, 0, 0);
}

// ---------------------------------------------------------------- f32 -> bf16 (weights)
__global__ void cvt_f2b_kernel(const float* __restrict__ in, u16* __restrict__ out, int n4) {
    int i = blockIdx.x * blockDim.x + threadIdx.x;
    if (i < n4) {
        float4 f = ((const float4*)in)[i];
        ((ushort4*)out)[i] = make_ushort4(f2bf(f.x), f2bf(f.y), f2bf(f.z), f2bf(f.w));
    }
}

__global__ void zero_kernel(u16* __restrict__ p, int n) {
    int i = blockIdx.x * blockDim.x + threadIdx.x;
    if (i < n) p[i] = 0;
}

// ---------------------------------------------------------------- LayerNorm over C=384, one wave per row
__global__ __launch_bounds__(64)
void ln_kernel(const float* __restrict__ xf, const float* __restrict__ g,
               const float* __restrict__ b, u16* __restrict__ out) {
    const int row = blockIdx.x;
    const int lane = threadIdx.x;
    const float* xr = xf + (size_t)row * 384;
    float v[6], s = 0.f, s2 = 0.f;
#pragma unroll
    for (int i = 0; i < 6; ++i) { v[i] = xr[lane + i * 64]; s += v[i]; s2 += v[i] * v[i]; }
#pragma unroll
    for (int off = 32; off; off >>= 1) { s += __shfl_xor(s, off); s2 += __shfl_xor(s2, off); }
    float mean = s * (1.0f / 384.0f);
    float var  = s2 * (1.0f / 384.0f) - mean * mean;
    float rstd = rsqrtf(var + LN_EPS);
    u16* orow = out + (size_t)row * 384;
#pragma unroll
    for (int i = 0; i < 6; ++i) {
        int c = lane + i * 64;
        orow[c] = f2bf((v[i] - mean) * rstd * g[c] + b[c]);
    }
}

// ---------------------------------------------------------------- MFMA NT GEMM: C[M,N] = A[M,K] * B[N,K]^T   (A,B bf16)
// 128x128 tile, BK=64, double-buffered LDS [128][64]/matrix with XOR chunk-swizzle:
//   LDS chunk (row, c) holds logical (row, c ^ (row&7))  (chunk = 16B = 8 bf16)
//   write side: linear gl_lds dest + inverse-permuted GLOBAL source (rule: both-sides-or-neither)
//   read  side: ds_read_b128 at chunk (kchunk ^ (fr&7))  -> conflict-free (2 lanes/bank-quad per qwave)
// Pipeline: compute tile t from buf[t&1] | barrier | issue tile t+2 into freed buf | vmcnt(8)
// (counted: drains t+1 which was issued a full tile earlier; t+2 stays in flight) | barrier.
// XCD-aware swizzle unchanged. ACONV: 0 = plain A[M,K]; 1 = implicit im2col (H=W=48, K=3456).
// EPI: 0 bf16 store; 1 BN+GELU->bf16; 2 BN -> xf += gamma*v; 3 xf += gamma*v;
//      4 ofb = xf + gamma*v; 5 xf = xin + gamma*v
template<int ACONV, int EPI>
__global__ __launch_bounds__(256, 2)
void gemm_nt(const u16* __restrict__ A, const u16* __restrict__ Bm,
             int M, int N, int K,
             u16* __restrict__ Obf, int ldo,
             float* __restrict__ xf, float* __restrict__ ofb, const float* __restrict__ xin,
             const float* __restrict__ bn_g, const float* __restrict__ bn_b,
             const float* __restrict__ bn_m, const float* __restrict__ bn_v,
             const float* __restrict__ gamma, const u16* __restrict__ zp) {
    __shared__ u16 As[2][128 * 64];
    __shared__ u16 Bs[2][128 * 64];

    const int tid = threadIdx.x;
    // XCD swizzle: L = (g%8)*(G/8) + g/8 ; n_tile = L % gx (fast), m_tile = L / gx (contiguous band/XCD)
    const int gx = gridDim.x;
    const int g  = blockIdx.y * gx + blockIdx.x;
    const int G  = gx * gridDim.y;
    int L = g;
    if ((G & 7) == 0) L = (g & 7) * (G >> 3) + (g >> 3);
    const int n0 = (L % gx) * 128;
    const int m0 = (L / gx) * 128;

    const int lane  = tid & 63;
    const int wave  = tid >> 6;
    const int wm    = (wave >> 1) * 64;
    const int wn    = (wave & 1) * 64;
    const int fr    = lane & 15;
    const int klane = lane >> 4;

    // ds_read address constants (u16 units): frag(i,kh) at row*64 + swizzled_chunk*8
    int arow[4], brow[4];
#pragma unroll
    for (int i = 0; i < 4; ++i) {
        arow[i] = (wm + i * 16 + fr) * 64;
        brow[i] = (wn + i * 16 + fr) * 64;
    }
    int csw[2];
#pragma unroll
    for (int kh = 0; kh < 2; ++kh) csw[kh] = ((((kh << 2) + klane) ^ (fr & 7)) << 3);

    // staging geometry: 1024 chunks per [128][64] tile, 4 chunks/thread/matrix
    // chunk ci = q*256 + tid -> row = ci>>3, c = ci&7; source logical chunk = c ^ (row&7)
    int sdst[4];                     // LDS chunk base offsets (u16), wave-uniform
    int ssc[4];                      // swizzled source col offset within 64-k window (u16)
    const u16 *sa[4], *sb[4];
    int ay[4], ax[4];
    const u16* img = nullptr;
#pragma unroll
    for (int q = 0; q < 4; ++q) {
        int ci  = q * 256 + tid;
        int row = ci >> 3;
        int c   = ci & 7;
        ssc[q]  = ((c ^ (row & 7)) << 3);
        sdst[q] = (q * 256 + wave * 64) << 3;
        sb[q]   = Bm + (size_t)(n0 + row) * K + ssc[q];
        if (ACONV == 0) {
            sa[q] = A + (size_t)(m0 + row) * K + ssc[q];
        } else {
            int nl = (m0 % 2304) + row;          // tile never crosses image (2304 = 18*128)
            ay[q] = nl / 48;
            ax[q] = nl - ay[q] * 48;
        }
    }
    if (ACONV == 1) img = A + (size_t)(m0 / 2304) * 2304 * 384;

    int scnt = 0, sjj = 0;
    const int NT = K / 64;

    auto STAGE = [&](int d) {
        if (ACONV == 1) {
            if (scnt == 0) {                     // new 3x3 tap: recompute A pointers
                int t3 = sjj / 3;
                int dy = t3 - 1, dx = sjj - t3 * 3 - 1;
                ++sjj;
#pragma unroll
                for (int q = 0; q < 4; ++q) {
                    int yy = ay[q] + dy, xx = ax[q] + dx;
                    bool v = ((unsigned)yy < 48u) & ((unsigned)xx < 48u);
                    sa[q] = (v ? img + (size_t)(yy * 48 + xx) * 384 : zp) + ssc[q];
                }
            }
            scnt = (scnt == 5) ? 0 : scnt + 1;
        }
        u16* la = &As[d][0];
        u16* lb = &Bs[d][0];
#pragma unroll
        for (int q = 0; q < 4; ++q) { gl_lds16(sa[q], la + sdst[q]); sa[q] += 64; }
#pragma unroll
        for (int q = 0; q < 4; ++q) { gl_lds16(sb[q], lb + sdst[q]); sb[q] += 64; }
    };

    floatx4 acc[4][4];
#pragma unroll
    for (int i = 0; i < 4; ++i)
#pragma unroll
        for (int j = 0; j < 4; ++j) acc[i][j] = (floatx4){0.f, 0.f, 0.f, 0.f};

    // prologue: tiles 0,1 in flight; wait tile 0 (counted: tile 1's 8 stay outstanding)
    STAGE(0);
    STAGE(1);
    asm volatile("s_waitcnt vmcnt(8)" ::: "memory");
    __builtin_amdgcn_s_barrier();
    asm volatile("" ::: "memory");

    int cur = 0;
    for (int t = 0; t < NT; ++t) {
        const u16* Ab = &As[cur][0];
        const u16* Bb = &Bs[cur][0];
#pragma unroll
        for (int kh = 0; kh < 2; ++kh) {
            short8 af[4], bfr[4];
#pragma unroll
            for (int i = 0; i < 4; ++i) af[i]  = *(const short8*)(Ab + arow[i] + csw[kh]);
#pragma unroll
            for (int j = 0; j < 4; ++j) bfr[j] = *(const short8*)(Bb + brow[j] + csw[kh]);
#pragma unroll
            for (int i = 0; i < 4; ++i)
#pragma unroll
                for (int j = 0; j < 4; ++j)
                    acc[i][j] = __builtin_amdgcn_mfma_f32_16x16x32_bf16(af[i], bfr[j], acc[i][j], 0, 0, 0);
        }
        asm volatile("s_waitcnt lgkmcnt(0)" ::: "memory");   // this wave's reads of buf[cur] done
        __builtin_amdgcn_s_barrier();                        // all waves done -> buf[cur] free
        asm volatile("" ::: "memory");
        if (t + 2 < NT) {
            STAGE(cur);                                      // issue tile t+2 into freed buffer
            asm volatile("s_waitcnt vmcnt(8)" ::: "memory"); // drain tile t+1 (issued 1 tile ago)
        } else {
            asm volatile("s_waitcnt vmcnt(0)" ::: "memory"); // tail: nothing new issued
        }
        __builtin_amdgcn_sched_barrier(0);
        __builtin_amdgcn_s_barrier();                        // tile t+1 resident for all waves
        asm volatile("" ::: "memory");
        cur ^= 1;
    }

    // Epilogue. C/D layout: col = lane&15, row = (lane>>4)*4 + reg   [verified m89/m91]
    const int quad4 = (lane >> 4) * 4;
#pragma unroll
    for (int j = 0; j < 4; ++j) {
        int col = n0 + wn + j * 16 + fr;
        float bscale = 0.f, bshift = 0.f, gam = 0.f;
        if (EPI == 1 || EPI == 2) {
            bscale = bn_g[col] * rsqrtf(bn_v[col] + LN_EPS);
            bshift = bn_b[col] - bn_m[col] * bscale;
        }
        if (EPI >= 2) gam = gamma[col];
#pragma unroll
        for (int i = 0; i < 4; ++i) {
#pragma unroll
            for (int r = 0; r < 4; ++r) {
                int row = m0 + wm + i * 16 + quad4 + r;
                float v = acc[i][j][r];
                if (EPI == 0) {
                    Obf[(size_t)row * ldo + col] = f2bf(v);
                } else if (EPI == 1) {
                    float t = v * bscale + bshift;
                    t = 0.5f * t * (1.0f + erff(t * 0.70710678118654752f));
                    Obf[(size_t)row * ldo + col] = f2bf(t);
                } else if (EPI == 2) {
                    float t = v * bscale + bshift;
                    xf[(size_t)row * N + col] += gam * t;
                } else if (EPI == 3) {
                    xf[(size_t)row * N + col] += gam * v;
                } else if (EPI == 4) {
                    ofb[(size_t)row * N + col] = xf[(size_t)row * N + col] + gam * v;
                } else {
                    xf[(size_t)row * N + col] = xin[(size_t)row * N + col] + gam * v;
                }
            }
        }
    }
}

// ---------------------------------------------------------------- channel attention: per (b,h) Gram + norms + softmax
__global__ __launch_bounds__(256)
void attn_kernel(const u16* __restrict__ qkv, const float* __restrict__ temp,
                 float* __restrict__ attnb) {
    const int bh = blockIdx.x;
    const int b = bh >> 3, h = bh & 7;
    const int tid = threadIdx.x;
    __shared__ float qsf[64][48];
    __shared__ float ksf[64][48];
    __shared__ float qns[48], kns[48];
    __shared__ float S[48][49];

    float acc9[3][3];
#pragma unroll
    for (int i = 0; i < 3; ++i)
#pragma unroll
        for (int j = 0; j < 3; ++j) acc9[i][j] = 0.f;
    float qn2 = 0.f, kn2 = 0.f;

    const int qoff = h * 48;
    const int koff = 384 + h * 48;
    const int d0 = (tid >> 4) * 3;
    const int e0 = (tid & 15) * 3;

    for (int n0 = 0; n0 < 2304; n0 += 64) {
#pragma unroll
        for (int it = 0; it < 6; ++it) {
            int chunk = tid + it * 256;          // 0..1535: [q 768 | k 768] chunks of 4 bf16
            int mat = chunk >= 768 ? 1 : 0;
            int rem = chunk - mat * 768;
            int nn = rem / 12, u = rem - nn * 12;
            ushort4 raw = *(const ushort4*)(qkv + (size_t)(b * 2304 + n0 + nn) * 1152 +
                                            (mat ? koff : qoff) + u * 4);
            float4 f = make_float4(bf2f(raw.x), bf2f(raw.y), bf2f(raw.z), bf2f(raw.w));
            if (mat) *(float4*)&ksf[nn][u * 4] = f;
            else     *(float4*)&qsf[nn][u * 4] = f;
        }
        __syncthreads();
#pragma unroll 4
        for (int nn = 0; nn < 64; ++nn) {
            float q0 = qsf[nn][d0], q1 = qsf[nn][d0 + 1], q2 = qsf[nn][d0 + 2];
            float k0v = ksf[nn][e0], k1v = ksf[nn][e0 + 1], k2v = ksf[nn][e0 + 2];
            acc9[0][0] += q0 * k0v; acc9[0][1] += q0 * k1v; acc9[0][2] += q0 * k2v;
            acc9[1][0] += q1 * k0v; acc9[1][1] += q1 * k1v; acc9[1][2] += q1 * k2v;
            acc9[2][0] += q2 * k0v; acc9[2][1] += q2 * k1v; acc9[2][2] += q2 * k2v;
        }
        if (tid < 48) {
            for (int nn = 0; nn < 64; ++nn) { float q = qsf[nn][tid]; qn2 += q * q; }
        } else if (tid >= 128 && tid < 176) {
            int e = tid - 128;
            for (int nn = 0; nn < 64; ++nn) { float k = ksf[nn][e]; kn2 += k * k; }
        }
        __syncthreads();
    }

    if (tid < 48) qns[tid] = fmaxf(sqrtf(qn2), 1e-12f);
    else if (tid >= 128 && tid < 176) kns[tid - 128] = fmaxf(sqrtf(kn2), 1e-12f);
    __syncthreads();

    float tf = temp[h];
#pragma unroll
    for (int i = 0; i < 3; ++i)
#pragma unroll
        for (int j = 0; j < 3; ++j)
            S[d0 + i][e0 + j] = acc9[i][j] * tf / (qns[d0 + i] * kns[e0 + j]);
    __syncthreads();

    if (tid < 48) {
        float mx = -1e30f;
        for (int e = 0; e < 48; ++e) mx = fmaxf(mx, S[tid][e]);
        float sum = 0.f;
        for (int e = 0; e < 48; ++e) { float t = __expf(S[tid][e] - mx); S[tid][e] = t; sum += t; }
        float inv = 1.0f / sum;
        float* dst = attnb + ((size_t)bh * 48 + tid) * 48;
        for (int e = 0; e < 48; ++e) dst[e] = S[tid][e] * inv;
    }
}

// ---------------------------------------------------------------- out[b,n,h*48+d] = sum_e attn[b,h,d,e] * v[b,n,h*48+e]
__global__ __launch_bounds__(256)
void attnout_kernel(const u16* __restrict__ qkv, const float* __restrict__ attnb,
                    u16* __restrict__ z) {
    const int r0 = blockIdx.x * 64;
    const int h  = blockIdx.y;
    const int b  = r0 / 2304;
    const int tid = threadIdx.x;
    __shared__ float A[48][49];
    __shared__ float vsf[64][48];

    const float* asrc = attnb + (size_t)(b * 8 + h) * 2304;
    for (int i = tid; i < 2304; i += 256) {
        int d = i / 48, e = i - d * 48;
        A[d][e] = asrc[i];
    }
    const int voff = 768 + h * 48;
    for (int i = tid; i < 768; i += 256) {
        int nn = i / 12, u = i - nn * 12;
        ushort4 raw = *(const ushort4*)(qkv + (size_t)(r0 + nn) * 1152 + voff + u * 4);
        float4 f = make_float4(bf2f(raw.x), bf2f(raw.y), bf2f(raw.z), bf2f(raw.w));
        *(float4*)&vsf[nn][u * 4] = f;
    }
    __syncthreads();

    const int rr0 = (tid >> 4) * 4;
    const int d0  = (tid & 15) * 3;
    float acc[4][3];
#pragma unroll
    for (int r = 0; r < 4; ++r)
#pragma unroll
        for (int j = 0; j < 3; ++j) acc[r][j] = 0.f;

#pragma unroll 4
    for (int e = 0; e < 48; ++e) {
        float a0 = A[d0][e], a1 = A[d0 + 1][e], a2 = A[d0 + 2][e];
#pragma unroll
        for (int r = 0; r < 4; ++r) {
            float vv = vsf[rr0 + r][e];
            acc[r][0] += a0 * vv; acc[r][1] += a1 * vv; acc[r][2] += a2 * vv;
        }
    }
#pragma unroll
    for (int r = 0; r < 4; ++r)
#pragma unroll
        for (int j = 0; j < 3; ++j)
            z[(size_t)(r0 + rr0 + r) * 384 + h * 48 + d0 + j] = f2bf(acc[r][j]);
}

// ---------------------------------------------------------------- conv weight: f32 [O,C,3,3] -> bf16 [O, (dy*3+dx)*384 + c]
__global__ void reorder_w_kernel(const float* __restrict__ w, u16* __restrict__ wr, int n) {
    int i = blockIdx.x * blockDim.x + threadIdx.x;
    if (i < n) {
        int o = i / 3456, rem = i - o * 3456;
        int j = rem / 384, c = rem - j * 384;
        wr[i] = f2bf(w[(size_t)(o * 384 + c) * 9 + j]);
    }
}

// ---------------------------------------------------------------- (H, W) tail
__global__ void tail_kernel(const int* __restrict__ Hp, const int* __restrict__ Wp,
                            float* __restrict__ out, size_t base, int n_extra) {
    if (threadIdx.x == 0) {
        if (n_extra >= 1) out[base]     = (float)Hp[0];
        if (n_extra >= 2) out[base + 1] = (float)Wp[0];
    }
}

extern "C" void kernel_launch(void* const* d_in, const int* in_sizes, int n_in,
                              void* d_out, int out_size, void* d_ws, size_t ws_size,
                              hipStream_t stream) {
    const float* x      = (const float*)d_in[0];
    const float* ln1_g  = (const float*)d_in[1];
    const float* ln1_b  = (const float*)d_in[2];
    const float* w_qkv  = (const float*)d_in[3];
    const float* temp   = (const float*)d_in[4];
    const float* w_proj = (const float*)d_in[5];
    const float* gamma1 = (const float*)d_in[6];
    const float* ln2_g  = (const float*)d_in[7];
    const float* ln2_b  = (const float*)d_in[8];
    const float* mlp_w1 = (const float*)d_in[9];
    const float* bn1_g  = (const float*)d_in[10];
    const float* bn1_b  = (const float*)d_in[11];
    const float* bn1_m  = (const float*)d_in[12];
    const float* bn1_v  = (const float*)d_in[13];
    const float* mlp_w2 = (const float*)d_in[14];
    const float* bn2_g  = (const float*)d_in[15];
    const float* bn2_b  = (const float*)d_in[16];
    const float* bn2_m  = (const float*)d_in[17];
    const float* bn2_v  = (const float*)d_in[18];
    const float* gamma2 = (const float*)d_in[19];
    const float* ln3_g  = (const float*)d_in[20];
    const float* ln3_b  = (const float*)d_in[21];
    const float* pconv1 = (const float*)d_in[22];
    const float* pbn_g  = (const float*)d_in[23];
    const float* pbn_b  = (const float*)d_in[24];
    const float* pbn_m  = (const float*)d_in[25];
    const float* pbn_v  = (const float*)d_in[26];
    const float* pconv2 = (const float*)d_in[27];
    const float* gamma3 = (const float*)d_in[28];
    const int* Hp = (const int*)d_in[29];
    const int* Wp = (const int*)d_in[30];

    const int M = 36864, C = 384, C2 = 768, NQKV = 1152, KC = 3456;
    const size_t NBNC = (size_t)M * C;                 // 14,155,776

    const size_t SZ_XF  = NBNC * 4;                    //  f32 residual stream
    const size_t SZ_LN  = NBNC * 2;                    //  bf16 LN out / attn z
    const size_t SZ_BIG = (size_t)M * NQKV * 2;        //  bf16 qkv / mlp hidden / zero page
    const size_t SZ_P3  = SZ_LN;                       //  attnb + bf16 weights, later conv1 out
    const size_t SZ_W   = (size_t)C * KC * 2;
    if (ws_size < SZ_XF + SZ_LN + SZ_BIG + SZ_P3 + 2 * SZ_W) return;

    char* ws = (char*)d_ws;
    float* xf     = (float*)ws;
    u16*   lnbuf  = (u16*)(ws + SZ_XF);
    u16*   big    = (u16*)(ws + SZ_XF + SZ_LN);
    char*  p3     = ws + SZ_XF + SZ_LN + SZ_BIG;
    float* attnb  = (float*)p3;                                      // 1,179,648 B
    u16*   wqkvb  = (u16*)(p3 + 1179648);
    u16*   wprojb = (u16*)(p3 + 1179648 + 884736);
    u16*   w1b    = (u16*)(p3 + 1179648 + 884736 + 294912);
    u16*   w2b    = (u16*)(p3 + 1179648 + 884736 + 294912 + 589824);
    u16*   convbf = (u16*)p3;                                        // conv1 output (bf16, M*C)
    u16*   w1r    = (u16*)(p3 + SZ_P3);
    u16*   w2r    = (u16*)(p3 + SZ_P3 + SZ_W);
    u16*   zp     = big;                                             // 4 KB zero page (big is dead in block 3)

    const int n_extra = out_size - (int)NBNC;

    // weight conversions (f32 -> bf16)
    cvt_f2b_kernel<<<(NQKV * C / 4 + 255) / 256, 256, 0, stream>>>(w_qkv, wqkvb, NQKV * C / 4);
    cvt_f2b_kernel<<<(C * C / 4 + 255) / 256, 256, 0, stream>>>(w_proj, wprojb, C * C / 4);
    cvt_f2b_kernel<<<(C2 * C / 4 + 255) / 256, 256, 0, stream>>>(mlp_w1, w1b, C2 * C / 4);
    cvt_f2b_kernel<<<(C * C2 / 4 + 255) / 256, 256, 0, stream>>>(mlp_w2, w2b, C * C2 / 4);

    // --- attention block ---  (ln1 reads input x directly; no residual copy)
    ln_kernel<<<M, 64, 0, stream>>>(x, ln1_g, ln1_b, lnbuf);
    gemm_nt<0, 0><<<dim3(NQKV / 128, M / 128), 256, 0, stream>>>(
        lnbuf, wqkvb, M, NQKV, C, big, NQKV, nullptr, nullptr, nullptr,
        nullptr, nullptr, nullptr, nullptr, nullptr, nullptr);
    attn_kernel<<<128, 256, 0, stream>>>(big, temp, attnb);
    attnout_kernel<<<dim3(M / 64, 8), 256, 0, stream>>>(big, attnb, lnbuf);
    gemm_nt<0, 5><<<dim3(C / 128, M / 128), 256, 0, stream>>>(        // xf = x + gamma1 * proj
        lnbuf, wprojb, M, C, C, nullptr, 0, xf, nullptr, x,
        nullptr, nullptr, nullptr, nullptr, gamma1, nullptr);

    // --- ConvMlp block (1x1 convs + eval BN) ---
    ln_kernel<<<M, 64, 0, stream>>>(xf, ln2_g, ln2_b, lnbuf);
    gemm_nt<0, 1><<<dim3(C2 / 128, M / 128), 256, 0, stream>>>(
        lnbuf, w1b, M, C2, C, big, C2, nullptr, nullptr, nullptr,
        bn1_g, bn1_b, bn1_m, bn1_v, nullptr, nullptr);
    gemm_nt<0, 2><<<dim3(C / 128, M / 128), 256, 0, stream>>>(
        big, w2b, M, C, C2, nullptr, 0, xf, nullptr, nullptr,
        bn2_g, bn2_b, bn2_m, bn2_v, gamma2, nullptr);

    // --- projection block (3x3 conv -> BN -> GELU -> 3x3 conv), implicit im2col GEMMs ---
    ln_kernel<<<M, 64, 0, stream>>>(xf, ln3_g, ln3_b, lnbuf);
    reorder_w_kernel<<<(C * KC + 255) / 256, 256, 0, stream>>>(pconv1, w1r, C * KC);
    reorder_w_kernel<<<(C * KC + 255) / 256, 256, 0, stream>>>(pconv2, w2r, C * KC);
    zero_kernel<<<8, 256, 0, stream>>>(zp, 2048);      // 4 KB zero page for im2col halo
    gemm_nt<1, 1><<<dim3(C / 128, M / 128), 256, 0, stream>>>(
        lnbuf, w1r, M, C, KC, convbf, C, nullptr, nullptr, nullptr,
        pbn_g, pbn_b, pbn_m, pbn_v, nullptr, zp);
    gemm_nt<1, 4><<<dim3(C / 128, M / 128), 256, 0, stream>>>(
        convbf, w2r, M, C, KC, nullptr, 0, xf, (float*)d_out, nullptr,
        nullptr, nullptr, nullptr, nullptr, gamma3, zp);

    tail_kernel<<<1, 64, 0, stream>>>(Hp, Wp, (float*)d_out, NBNC, n_extra);
}

// Round 2
// 805.729 us; speedup vs baseline: 1.1166x; 1.0591x over previous
//
#include <hip/hip_runtime.h>
#include <hip/hip_bf16.h>

typedef unsigned short u16;
typedef __attribute__((ext_vector_type(8))) short short8;   // 8 bf16 (4 VGPRs) — MFMA A/B frag
typedef __attribute__((ext_vector_type(4))) float floatx4;  // MFMA C/D frag

#define LN_EPS 1e-5f

__device__ __forceinline__ float bf2f(u16 u) {
    unsigned int i = ((unsigned int)u) << 16;
    float f; __builtin_memcpy(&f, &i, 4); return f;
}
__device__ __forceinline__ u16 f2bf(float f) {
    __hip_bfloat16 h = __float2bfloat16(f);   // RNE
    u16 u; __builtin_memcpy(&u, &h, 2); return u;
}

// async global->LDS, 16 B per lane; lds dest must be wave-uniform (HW adds lane*16)
__device__ __forceinline__ void gl_lds16(const u16* g, u16* l) {
    __builtin_amdgcn_global_load_lds(
        (const __attribute__((address_space(1))) void*)(const void*)g,
        (__attribute__((address_space(3))) void*)(void*)l,
        16, 0, 0);
}

// ---------------------------------------------------------------- f32 -> bf16 (weights)
__global__ void cvt_f2b_kernel(const float* __restrict__ in, u16* __restrict__ out, int n4) {
    int i = blockIdx.x * blockDim.x + threadIdx.x;
    if (i < n4) {
        float4 f = ((const float4*)in)[i];
        ((ushort4*)out)[i] = make_ushort4(f2bf(f.x), f2bf(f.y), f2bf(f.z), f2bf(f.w));
    }
}

__global__ void zero_kernel(u16* __restrict__ p, int n) {
    int i = blockIdx.x * blockDim.x + threadIdx.x;
    if (i < n) p[i] = 0;
}

__global__ void zero_f32_kernel(float* __restrict__ p, int n) {
    int i = blockIdx.x * blockDim.x + threadIdx.x;
    if (i < n) p[i] = 0.f;
}

// ---------------------------------------------------------------- LayerNorm over C=384, one wave per row
__global__ __launch_bounds__(64)
void ln_kernel(const float* __restrict__ xf, const float* __restrict__ g,
               const float* __restrict__ b, u16* __restrict__ out) {
    const int row = blockIdx.x;
    const int lane = threadIdx.x;
    const float* xr = xf + (size_t)row * 384;
    float v[6], s = 0.f, s2 = 0.f;
#pragma unroll
    for (int i = 0; i < 6; ++i) { v[i] = xr[lane + i * 64]; s += v[i]; s2 += v[i] * v[i]; }
#pragma unroll
    for (int off = 32; off; off >>= 1) { s += __shfl_xor(s, off); s2 += __shfl_xor(s2, off); }
    float mean = s * (1.0f / 384.0f);
    float var  = s2 * (1.0f / 384.0f) - mean * mean;
    float rstd = rsqrtf(var + LN_EPS);
    u16* orow = out + (size_t)row * 384;
#pragma unroll
    for (int i = 0; i < 6; ++i) {
        int c = lane + i * 64;
        orow[c] = f2bf((v[i] - mean) * rstd * g[c] + b[c]);
    }
}

// ---------------------------------------------------------------- MFMA NT GEMM: C[M,N] = A[M,K] * B[N,K]^T   (A,B bf16)
// 128x128 tile, BK=64, double-buffered LDS [128][64]/matrix with XOR chunk-swizzle:
//   LDS chunk (row, c) holds logical (row, c ^ (row&7))  (chunk = 16B = 8 bf16)
//   write side: linear gl_lds dest + inverse-permuted GLOBAL source (rule: both-sides-or-neither)
//   read  side: ds_read_b128 at chunk (kchunk ^ (fr&7))  -> conflict-free (2 lanes/bank-quad per qwave)
// Pipeline: compute tile t from buf[t&1] | barrier | issue tile t+2 into freed buf | vmcnt(8)
// (counted: drains t+1 which was issued a full tile earlier; t+2 stays in flight) | barrier.
// XCD-aware swizzle unchanged. ACONV: 0 = plain A[M,K]; 1 = implicit im2col (H=W=48, K=3456).
// EPI: 0 bf16 store; 1 BN+GELU->bf16; 2 BN -> xf += gamma*v; 3 xf += gamma*v;
//      4 ofb = xf + gamma*v; 5 xf = xin + gamma*v
template<int ACONV, int EPI>
__global__ __launch_bounds__(256, 2)
void gemm_nt(const u16* __restrict__ A, const u16* __restrict__ Bm,
             int M, int N, int K,
             u16* __restrict__ Obf, int ldo,
             float* __restrict__ xf, float* __restrict__ ofb, const float* __restrict__ xin,
             const float* __restrict__ bn_g, const float* __restrict__ bn_b,
             const float* __restrict__ bn_m, const float* __restrict__ bn_v,
             const float* __restrict__ gamma, const u16* __restrict__ zp) {
    __shared__ u16 As[2][128 * 64];
    __shared__ u16 Bs[2][128 * 64];

    const int tid = threadIdx.x;
    // XCD swizzle: L = (g%8)*(G/8) + g/8 ; n_tile = L % gx (fast), m_tile = L / gx (contiguous band/XCD)
    const int gx = gridDim.x;
    const int g  = blockIdx.y * gx + blockIdx.x;
    const int G  = gx * gridDim.y;
    int L = g;
    if ((G & 7) == 0) L = (g & 7) * (G >> 3) + (g >> 3);
    const int n0 = (L % gx) * 128;
    const int m0 = (L / gx) * 128;

    const int lane  = tid & 63;
    const int wave  = tid >> 6;
    const int wm    = (wave >> 1) * 64;
    const int wn    = (wave & 1) * 64;
    const int fr    = lane & 15;
    const int klane = lane >> 4;

    // ds_read address constants (u16 units): frag(i,kh) at row*64 + swizzled_chunk*8
    int arow[4], brow[4];
#pragma unroll
    for (int i = 0; i < 4; ++i) {
        arow[i] = (wm + i * 16 + fr) * 64;
        brow[i] = (wn + i * 16 + fr) * 64;
    }
    int csw[2];
#pragma unroll
    for (int kh = 0; kh < 2; ++kh) csw[kh] = ((((kh << 2) + klane) ^ (fr & 7)) << 3);

    // staging geometry: 1024 chunks per [128][64] tile, 4 chunks/thread/matrix
    // chunk ci = q*256 + tid -> row = ci>>3, c = ci&7; source logical chunk = c ^ (row&7)
    int sdst[4];                     // LDS chunk base offsets (u16), wave-uniform
    int ssc[4];                      // swizzled source col offset within 64-k window (u16)
    const u16 *sa[4], *sb[4];
    int ay[4], ax[4];
    const u16* img = nullptr;
#pragma unroll
    for (int q = 0; q < 4; ++q) {
        int ci  = q * 256 + tid;
        int row = ci >> 3;
        int c   = ci & 7;
        ssc[q]  = ((c ^ (row & 7)) << 3);
        sdst[q] = (q * 256 + wave * 64) << 3;
        sb[q]   = Bm + (size_t)(n0 + row) * K + ssc[q];
        if (ACONV == 0) {
            sa[q] = A + (size_t)(m0 + row) * K + ssc[q];
        } else {
            int nl = (m0 % 2304) + row;          // tile never crosses image (2304 = 18*128)
            ay[q] = nl / 48;
            ax[q] = nl - ay[q] * 48;
        }
    }
    if (ACONV == 1) img = A + (size_t)(m0 / 2304) * 2304 * 384;

    int scnt = 0, sjj = 0;
    const int NT = K / 64;

    auto STAGE = [&](int d) {
        if (ACONV == 1) {
            if (scnt == 0) {                     // new 3x3 tap: recompute A pointers
                int t3 = sjj / 3;
                int dy = t3 - 1, dx = sjj - t3 * 3 - 1;
                ++sjj;
#pragma unroll
                for (int q = 0; q < 4; ++q) {
                    int yy = ay[q] + dy, xx = ax[q] + dx;
                    bool v = ((unsigned)yy < 48u) & ((unsigned)xx < 48u);
                    sa[q] = (v ? img + (size_t)(yy * 48 + xx) * 384 : zp) + ssc[q];
                }
            }
            scnt = (scnt == 5) ? 0 : scnt + 1;
        }
        u16* la = &As[d][0];
        u16* lb = &Bs[d][0];
#pragma unroll
        for (int q = 0; q < 4; ++q) { gl_lds16(sa[q], la + sdst[q]); sa[q] += 64; }
#pragma unroll
        for (int q = 0; q < 4; ++q) { gl_lds16(sb[q], lb + sdst[q]); sb[q] += 64; }
    };

    floatx4 acc[4][4];
#pragma unroll
    for (int i = 0; i < 4; ++i)
#pragma unroll
        for (int j = 0; j < 4; ++j) acc[i][j] = (floatx4){0.f, 0.f, 0.f, 0.f};

    // prologue: tiles 0,1 in flight; wait tile 0 (counted: tile 1's 8 stay outstanding)
    STAGE(0);
    STAGE(1);
    asm volatile("s_waitcnt vmcnt(8)" ::: "memory");
    __builtin_amdgcn_s_barrier();
    asm volatile("" ::: "memory");

    int cur = 0;
    for (int t = 0; t < NT; ++t) {
        const u16* Ab = &As[cur][0];
        const u16* Bb = &Bs[cur][0];
#pragma unroll
        for (int kh = 0; kh < 2; ++kh) {
            short8 af[4], bfr[4];
#pragma unroll
            for (int i = 0; i < 4; ++i) af[i]  = *(const short8*)(Ab + arow[i] + csw[kh]);
#pragma unroll
            for (int j = 0; j < 4; ++j) bfr[j] = *(const short8*)(Bb + brow[j] + csw[kh]);
#pragma unroll
            for (int i = 0; i < 4; ++i)
#pragma unroll
                for (int j = 0; j < 4; ++j)
                    acc[i][j] = __builtin_amdgcn_mfma_f32_16x16x32_bf16(af[i], bfr[j], acc[i][j], 0, 0, 0);
        }
        asm volatile("s_waitcnt lgkmcnt(0)" ::: "memory");   // this wave's reads of buf[cur] done
        __builtin_amdgcn_s_barrier();                        // all waves done -> buf[cur] free
        asm volatile("" ::: "memory");
        if (t + 2 < NT) {
            STAGE(cur);                                      // issue tile t+2 into freed buffer
            asm volatile("s_waitcnt vmcnt(8)" ::: "memory"); // drain tile t+1 (issued 1 tile ago)
        } else {
            asm volatile("s_waitcnt vmcnt(0)" ::: "memory"); // tail: nothing new issued
        }
        __builtin_amdgcn_sched_barrier(0);
        __builtin_amdgcn_s_barrier();                        // tile t+1 resident for all waves
        asm volatile("" ::: "memory");
        cur ^= 1;
    }

    // Epilogue. C/D layout: col = lane&15, row = (lane>>4)*4 + reg   [verified m89/m91]
    const int quad4 = (lane >> 4) * 4;
#pragma unroll
    for (int j = 0; j < 4; ++j) {
        int col = n0 + wn + j * 16 + fr;
        float bscale = 0.f, bshift = 0.f, gam = 0.f;
        if (EPI == 1 || EPI == 2) {
            bscale = bn_g[col] * rsqrtf(bn_v[col] + LN_EPS);
            bshift = bn_b[col] - bn_m[col] * bscale;
        }
        if (EPI >= 2) gam = gamma[col];
#pragma unroll
        for (int i = 0; i < 4; ++i) {
#pragma unroll
            for (int r = 0; r < 4; ++r) {
                int row = m0 + wm + i * 16 + quad4 + r;
                float v = acc[i][j][r];
                if (EPI == 0) {
                    Obf[(size_t)row * ldo + col] = f2bf(v);
                } else if (EPI == 1) {
                    float t = v * bscale + bshift;
                    t = 0.5f * t * (1.0f + erff(t * 0.70710678118654752f));
                    Obf[(size_t)row * ldo + col] = f2bf(t);
                } else if (EPI == 2) {
                    float t = v * bscale + bshift;
                    xf[(size_t)row * N + col] += gam * t;
                } else if (EPI == 3) {
                    xf[(size_t)row * N + col] += gam * v;
                } else if (EPI == 4) {
                    ofb[(size_t)row * N + col] = xf[(size_t)row * N + col] + gam * v;
                } else {
                    xf[(size_t)row * N + col] = xin[(size_t)row * N + col] + gam * v;
                }
            }
        }
    }
}

// ---------------------------------------------------------------- channel attention, stage 1:
// partial Gram + partial norms over a 128-row N-slice; atomicAdd into f32 accumulators.
// grid (18 slices, 128 bh); each (d,e) cell owned by exactly one thread per block.
__global__ __launch_bounds__(256)
void gram_kernel(const u16* __restrict__ qkv, float* __restrict__ Sacc,
                 float* __restrict__ nrm2) {
    const int bh = blockIdx.y;
    const int b = bh >> 3, h = bh & 7;
    const int tid = threadIdx.x;
    __shared__ float qsf[64][48];
    __shared__ float ksf[64][48];

    float acc9[3][3];
#pragma unroll
    for (int i = 0; i < 3; ++i)
#pragma unroll
        for (int j = 0; j < 3; ++j) acc9[i][j] = 0.f;
    float qn2 = 0.f, kn2 = 0.f;

    const int qoff = h * 48;
    const int koff = 384 + h * 48;
    const int d0 = (tid >> 4) * 3;
    const int e0 = (tid & 15) * 3;
    const int nbase = blockIdx.x * 128;

    for (int c = 0; c < 2; ++c) {
        const int n0 = nbase + c * 64;
#pragma unroll
        for (int it = 0; it < 6; ++it) {
            int chunk = tid + it * 256;          // 0..1535: [q 768 | k 768] chunks of 4 bf16
            int mat = chunk >= 768 ? 1 : 0;
            int rem = chunk - mat * 768;
            int nn = rem / 12, u = rem - nn * 12;
            ushort4 raw = *(const ushort4*)(qkv + (size_t)(b * 2304 + n0 + nn) * 1152 +
                                            (mat ? koff : qoff) + u * 4);
            float4 f = make_float4(bf2f(raw.x), bf2f(raw.y), bf2f(raw.z), bf2f(raw.w));
            if (mat) *(float4*)&ksf[nn][u * 4] = f;
            else     *(float4*)&qsf[nn][u * 4] = f;
        }
        __syncthreads();
#pragma unroll 4
        for (int nn = 0; nn < 64; ++nn) {
            float q0 = qsf[nn][d0], q1 = qsf[nn][d0 + 1], q2 = qsf[nn][d0 + 2];
            float k0v = ksf[nn][e0], k1v = ksf[nn][e0 + 1], k2v = ksf[nn][e0 + 2];
            acc9[0][0] += q0 * k0v; acc9[0][1] += q0 * k1v; acc9[0][2] += q0 * k2v;
            acc9[1][0] += q1 * k0v; acc9[1][1] += q1 * k1v; acc9[1][2] += q1 * k2v;
            acc9[2][0] += q2 * k0v; acc9[2][1] += q2 * k1v; acc9[2][2] += q2 * k2v;
        }
        if (tid < 48) {
            for (int nn = 0; nn < 64; ++nn) { float q = qsf[nn][tid]; qn2 += q * q; }
        } else if (tid >= 128 && tid < 176) {
            int e = tid - 128;
            for (int nn = 0; nn < 64; ++nn) { float k = ksf[nn][e]; kn2 += k * k; }
        }
        __syncthreads();
    }

    float* Sb = Sacc + (size_t)bh * 2304;
#pragma unroll
    for (int i = 0; i < 3; ++i)
#pragma unroll
        for (int j = 0; j < 3; ++j)
            atomicAdd(&Sb[(d0 + i) * 48 + e0 + j], acc9[i][j]);
    if (tid < 48) atomicAdd(&nrm2[bh * 96 + tid], qn2);
    else if (tid >= 128 && tid < 176) atomicAdd(&nrm2[bh * 96 + 48 + (tid - 128)], kn2);
}

// ---------------------------------------------------------------- channel attention, stage 2:
// scale by temperature / (|q| |k|), row softmax, write attnb. grid 128.
__global__ __launch_bounds__(256)
void attn_fin_kernel(const float* __restrict__ Sacc, const float* __restrict__ nrm2,
                     const float* __restrict__ temp, float* __restrict__ attnb) {
    const int bh = blockIdx.x;
    const int h = bh & 7;
    const int tid = threadIdx.x;
    __shared__ float S[48][49];
    __shared__ float qns[48], kns[48];

    const float* Sb = Sacc + (size_t)bh * 2304;
    for (int i = tid; i < 2304; i += 256) {
        int d = i / 48, e = i - d * 48;
        S[d][e] = Sb[i];
    }
    if (tid < 48)      qns[tid]      = fmaxf(sqrtf(nrm2[bh * 96 + tid]), 1e-12f);
    else if (tid < 96) kns[tid - 48] = fmaxf(sqrtf(nrm2[bh * 96 + tid]), 1e-12f);
    __syncthreads();

    if (tid < 48) {
        float tf = temp[h] / qns[tid];
        float mx = -1e30f;
        for (int e = 0; e < 48; ++e) {
            float t = S[tid][e] * tf / kns[e];
            S[tid][e] = t;
            mx = fmaxf(mx, t);
        }
        float sum = 0.f;
        for (int e = 0; e < 48; ++e) { float t = __expf(S[tid][e] - mx); S[tid][e] = t; sum += t; }
        float inv = 1.0f / sum;
        float* dst = attnb + ((size_t)bh * 48 + tid) * 48;
        for (int e = 0; e < 48; ++e) dst[e] = S[tid][e] * inv;
    }
}

// ---------------------------------------------------------------- out[b,n,h*48+d] = sum_e attn[b,h,d,e] * v[b,n,h*48+e]
__global__ __launch_bounds__(256)
void attnout_kernel(const u16* __restrict__ qkv, const float* __restrict__ attnb,
                    u16* __restrict__ z) {
    const int r0 = blockIdx.x * 64;
    const int h  = blockIdx.y;
    const int b  = r0 / 2304;
    const int tid = threadIdx.x;
    __shared__ float A[48][49];
    __shared__ float vsf[64][48];

    const float* asrc = attnb + (size_t)(b * 8 + h) * 2304;
    for (int i = tid; i < 2304; i += 256) {
        int d = i / 48, e = i - d * 48;
        A[d][e] = asrc[i];
    }
    const int voff = 768 + h * 48;
    for (int i = tid; i < 768; i += 256) {
        int nn = i / 12, u = i - nn * 12;
        ushort4 raw = *(const ushort4*)(qkv + (size_t)(r0 + nn) * 1152 + voff + u * 4);
        float4 f = make_float4(bf2f(raw.x), bf2f(raw.y), bf2f(raw.z), bf2f(raw.w));
        *(float4*)&vsf[nn][u * 4] = f;
    }
    __syncthreads();

    const int rr0 = (tid >> 4) * 4;
    const int d0  = (tid & 15) * 3;
    float acc[4][3];
#pragma unroll
    for (int r = 0; r < 4; ++r)
#pragma unroll
        for (int j = 0; j < 3; ++j) acc[r][j] = 0.f;

#pragma unroll 4
    for (int e = 0; e < 48; ++e) {
        float a0 = A[d0][e], a1 = A[d0 + 1][e], a2 = A[d0 + 2][e];
#pragma unroll
        for (int r = 0; r < 4; ++r) {
            float vv = vsf[rr0 + r][e];
            acc[r][0] += a0 * vv; acc[r][1] += a1 * vv; acc[r][2] += a2 * vv;
        }
    }
#pragma unroll
    for (int r = 0; r < 4; ++r)
#pragma unroll
        for (int j = 0; j < 3; ++j)
            z[(size_t)(r0 + rr0 + r) * 384 + h * 48 + d0 + j] = f2bf(acc[r][j]);
}

// ---------------------------------------------------------------- conv weight: f32 [O,C,3,3] -> bf16 [O, (dy*3+dx)*384 + c]
__global__ void reorder_w_kernel(const float* __restrict__ w, u16* __restrict__ wr, int n) {
    int i = blockIdx.x * blockDim.x + threadIdx.x;
    if (i < n) {
        int o = i / 3456, rem = i - o * 3456;
        int j = rem / 384, c = rem - j * 384;
        wr[i] = f2bf(w[(size_t)(o * 384 + c) * 9 + j]);
    }
}

// ---------------------------------------------------------------- (H, W) tail
__global__ void tail_kernel(const int* __restrict__ Hp, const int* __restrict__ Wp,
                            float* __restrict__ out, size_t base, int n_extra) {
    if (threadIdx.x == 0) {
        if (n_extra >= 1) out[base]     = (float)Hp[0];
        if (n_extra >= 2) out[base + 1] = (float)Wp[0];
    }
}

extern "C" void kernel_launch(void* const* d_in, const int* in_sizes, int n_in,
                              void* d_out, int out_size, void* d_ws, size_t ws_size,
                              hipStream_t stream) {
    const float* x      = (const float*)d_in[0];
    const float* ln1_g  = (const float*)d_in[1];
    const float* ln1_b  = (const float*)d_in[2];
    const float* w_qkv  = (const float*)d_in[3];
    const float* temp   = (const float*)d_in[4];
    const float* w_proj = (const float*)d_in[5];
    const float* gamma1 = (const float*)d_in[6];
    const float* ln2_g  = (const float*)d_in[7];
    const float* ln2_b  = (const float*)d_in[8];
    const float* mlp_w1 = (const float*)d_in[9];
    const float* bn1_g  = (const float*)d_in[10];
    const float* bn1_b  = (const float*)d_in[11];
    const float* bn1_m  = (const float*)d_in[12];
    const float* bn1_v  = (const float*)d_in[13];
    const float* mlp_w2 = (const float*)d_in[14];
    const float* bn2_g  = (const float*)d_in[15];
    const float* bn2_b  = (const float*)d_in[16];
    const float* bn2_m  = (const float*)d_in[17];
    const float* bn2_v  = (const float*)d_in[18];
    const float* gamma2 = (const float*)d_in[19];
    const float* ln3_g  = (const float*)d_in[20];
    const float* ln3_b  = (const float*)d_in[21];
    const float* pconv1 = (const float*)d_in[22];
    const float* pbn_g  = (const float*)d_in[23];
    const float* pbn_b  = (const float*)d_in[24];
    const float* pbn_m  = (const float*)d_in[25];
    const float* pbn_v  = (const float*)d_in[26];
    const float* pconv2 = (const float*)d_in[27];
    const float* gamma3 = (const float*)d_in[28];
    const int* Hp = (const int*)d_in[29];
    const int* Wp = (const int*)d_in[30];

    const int M = 36864, C = 384, C2 = 768, NQKV = 1152, KC = 3456;
    const size_t NBNC = (size_t)M * C;                 // 14,155,776

    const size_t SZ_XF  = NBNC * 4;                    //  f32 residual stream
    const size_t SZ_LN  = NBNC * 2;                    //  bf16 LN out / attn z
    const size_t SZ_BIG = (size_t)M * NQKV * 2;        //  bf16 qkv / mlp hidden / zero page
    const size_t SZ_P3  = SZ_LN;                       //  attnb + bf16 weights + Gram accum, later conv1 out
    const size_t SZ_W   = (size_t)C * KC * 2;
    if (ws_size < SZ_XF + SZ_LN + SZ_BIG + SZ_P3 + 2 * SZ_W) return;

    char* ws = (char*)d_ws;
    float* xf     = (float*)ws;
    u16*   lnbuf  = (u16*)(ws + SZ_XF);
    u16*   big    = (u16*)(ws + SZ_XF + SZ_LN);
    char*  p3     = ws + SZ_XF + SZ_LN + SZ_BIG;
    float* attnb  = (float*)p3;                                      // 1,179,648 B
    u16*   wqkvb  = (u16*)(p3 + 1179648);
    u16*   wprojb = (u16*)(p3 + 1179648 + 884736);
    u16*   w1b    = (u16*)(p3 + 1179648 + 884736 + 294912);
    u16*   w2b    = (u16*)(p3 + 1179648 + 884736 + 294912 + 589824);
    float* Sacc   = (float*)(p3 + 3538944);                          // 128*2304 f32 = 1,179,648 B
    float* nrm2   = (float*)(p3 + 3538944 + 1179648);                // 128*96 f32 = 49,152 B
    u16*   convbf = (u16*)p3;                                        // conv1 output (bf16, M*C), block 3 only
    u16*   w1r    = (u16*)(p3 + SZ_P3);
    u16*   w2r    = (u16*)(p3 + SZ_P3 + SZ_W);
    u16*   zp     = big;                                             // 4 KB zero page (big is dead in block 3)

    const int n_extra = out_size - (int)NBNC;

    // weight conversions (f32 -> bf16) + Gram accumulator zeroing
    cvt_f2b_kernel<<<(NQKV * C / 4 + 255) / 256, 256, 0, stream>>>(w_qkv, wqkvb, NQKV * C / 4);
    cvt_f2b_kernel<<<(C * C / 4 + 255) / 256, 256, 0, stream>>>(w_proj, wprojb, C * C / 4);
    cvt_f2b_kernel<<<(C2 * C / 4 + 255) / 256, 256, 0, stream>>>(mlp_w1, w1b, C2 * C / 4);
    cvt_f2b_kernel<<<(C * C2 / 4 + 255) / 256, 256, 0, stream>>>(mlp_w2, w2b, C * C2 / 4);
    zero_f32_kernel<<<(128 * 2304 + 128 * 96 + 255) / 256, 256, 0, stream>>>(
        Sacc, 128 * 2304 + 128 * 96);                // nrm2 is contiguous after Sacc

    // --- attention block ---  (ln1 reads input x directly; no residual copy)
    ln_kernel<<<M, 64, 0, stream>>>(x, ln1_g, ln1_b, lnbuf);
    gemm_nt<0, 0><<<dim3(NQKV / 128, M / 128), 256, 0, stream>>>(
        lnbuf, wqkvb, M, NQKV, C, big, NQKV, nullptr, nullptr, nullptr,
        nullptr, nullptr, nullptr, nullptr, nullptr, nullptr);
    gram_kernel<<<dim3(18, 128), 256, 0, stream>>>(big, Sacc, nrm2);
    attn_fin_kernel<<<128, 256, 0, stream>>>(Sacc, nrm2, temp, attnb);
    attnout_kernel<<<dim3(M / 64, 8), 256, 0, stream>>>(big, attnb, lnbuf);
    gemm_nt<0, 5><<<dim3(C / 128, M / 128), 256, 0, stream>>>(        // xf = x + gamma1 * proj
        lnbuf, wprojb, M, C, C, nullptr, 0, xf, nullptr, x,
        nullptr, nullptr, nullptr, nullptr, gamma1, nullptr);

    // --- ConvMlp block (1x1 convs + eval BN) ---
    ln_kernel<<<M, 64, 0, stream>>>(xf, ln2_g, ln2_b, lnbuf);
    gemm_nt<0, 1><<<dim3(C2 / 128, M / 128), 256, 0, stream>>>(
        lnbuf, w1b, M, C2, C, big, C2, nullptr, nullptr, nullptr,
        bn1_g, bn1_b, bn1_m, bn1_v, nullptr, nullptr);
    gemm_nt<0, 2><<<dim3(C / 128, M / 128), 256, 0, stream>>>(
        big, w2b, M, C, C2, nullptr, 0, xf, nullptr, nullptr,
        bn2_g, bn2_b, bn2_m, bn2_v, gamma2, nullptr);

    // --- projection block (3x3 conv -> BN -> GELU -> 3x3 conv), implicit im2col GEMMs ---
    ln_kernel<<<M, 64, 0, stream>>>(xf, ln3_g, ln3_b, lnbuf);
    reorder_w_kernel<<<(C * KC + 255) / 256, 256, 0, stream>>>(pconv1, w1r, C * KC);
    reorder_w_kernel<<<(C * KC + 255) / 256, 256, 0, stream>>>(pconv2, w2r, C * KC);
    zero_kernel<<<8, 256, 0, stream>>>(zp, 2048);      // 4 KB zero page for im2col halo
    gemm_nt<1, 1><<<dim3(C / 128, M / 128), 256, 0, stream>>>(
        lnbuf, w1r, M, C, KC, convbf, C, nullptr, nullptr, nullptr,
        pbn_g, pbn_b, pbn_m, pbn_v, nullptr, zp);
    gemm_nt<1, 4><<<dim3(C / 128, M / 128), 256, 0, stream>>>(
        convbf, w2r, M, C, KC, nullptr, 0, xf, (float*)d_out, nullptr,
        nullptr, nullptr, nullptr, nullptr, gamma3, zp);

    tail_kernel<<<1, 64, 0, stream>>>(Hp, Wp, (float*)d_out, NBNC, n_extra);
}